// Round 1
// baseline (2997.145 us; speedup 1.0000x reference)
//
#include <hip/hip_runtime.h>
#include <hip/hip_bf16.h>
#include <math.h>

typedef __attribute__((ext_vector_type(4))) float f32x4;
typedef __attribute__((ext_vector_type(8))) short bf16x8;
typedef __attribute__((ext_vector_type(8))) unsigned short u16x8;

#define D_MODEL 1024
#define DFF 2048
#define S_LEN 2048
#define T_TOK 4096
#define NEXP 8

__device__ __forceinline__ unsigned short f2bf(float f){
  union { float f; unsigned u; } v; v.f = f;
  unsigned u = v.u;
  u += 0x7fffu + ((u >> 16) & 1u);
  return (unsigned short)(u >> 16);
}

// ---------------- RMSNorm: one block per token ----------------
__global__ __launch_bounds__(256) void k_rmsnorm(const float* __restrict__ x,
    const float* __restrict__ w, float* __restrict__ out){
  const int t = blockIdx.x;
  const int tid = threadIdx.x;
  const float* row = x + (size_t)t * D_MODEL;
  float4 v = *(const float4*)(row + tid * 4);
  float ss = v.x*v.x + v.y*v.y + v.z*v.z + v.w*v.w;
  #pragma unroll
  for (int m = 1; m < 64; m <<= 1) ss += __shfl_xor(ss, m);
  __shared__ float red[4];
  if ((tid & 63) == 0) red[tid >> 6] = ss;
  __syncthreads();
  float tot = red[0] + red[1] + red[2] + red[3];
  float mean = tot * (1.0f / D_MODEL);
  float r = (float)(1.0 / sqrt((double)mean + 1e-6));
  float4 wv = *(const float4*)(w + tid * 4);
  float4 o;
  o.x = v.x * r * wv.x; o.y = v.y * r * wv.y;
  o.z = v.z * r * wv.z; o.w = v.w * r * wv.w;
  *(float4*)(out + (size_t)t * D_MODEL + tid * 4) = o;
}

// ---------------- fp32 GEMM: C[m,n] = sum_k A[m,k]*B[n,k] (+resid) ----------------
// 128x128 tile, BK=16, 256 threads, 8x8 microtile. B selected among up to 3
// row-major (N_i x K) weight blocks by n-tile (tiles never straddle boundaries).
__global__ __launch_bounds__(256) void k_gemm_f32(
    const float* __restrict__ A, int lda,
    const float* __restrict__ B0, const float* __restrict__ B1, const float* __restrict__ B2,
    int nb1, int nb2,
    float* __restrict__ C, int ldc,
    const float* __restrict__ resid, int K)
{
  __shared__ float As[16][132];
  __shared__ float Bs[16][132];
  const int n0 = blockIdx.x * 128, m0 = blockIdx.y * 128;
  const float* Bp; int nsub;
  if (B2 && n0 >= nb2)      { Bp = B2; nsub = n0 - nb2; }
  else if (B1 && n0 >= nb1) { Bp = B1; nsub = n0 - nb1; }
  else                      { Bp = B0; nsub = n0; }
  const int tid = threadIdx.x;
  const int sr = tid >> 1, sc = (tid & 1) << 3;
  const float* ap = A + (size_t)(m0 + sr) * lda + sc;
  const float* bp = Bp + (size_t)(nsub + sr) * K + sc;
  float acc[8][8];
  #pragma unroll
  for (int i = 0; i < 8; i++)
    #pragma unroll
    for (int j = 0; j < 8; j++) acc[i][j] = 0.f;
  const int tm = (tid >> 4) << 3, tn = (tid & 15) << 3;
  for (int k0 = 0; k0 < K; k0 += 16){
    float4 a0 = *(const float4*)(ap + k0);
    float4 a1 = *(const float4*)(ap + k0 + 4);
    float4 b0 = *(const float4*)(bp + k0);
    float4 b1 = *(const float4*)(bp + k0 + 4);
    As[sc+0][sr] = a0.x; As[sc+1][sr] = a0.y; As[sc+2][sr] = a0.z; As[sc+3][sr] = a0.w;
    As[sc+4][sr] = a1.x; As[sc+5][sr] = a1.y; As[sc+6][sr] = a1.z; As[sc+7][sr] = a1.w;
    Bs[sc+0][sr] = b0.x; Bs[sc+1][sr] = b0.y; Bs[sc+2][sr] = b0.z; Bs[sc+3][sr] = b0.w;
    Bs[sc+4][sr] = b1.x; Bs[sc+5][sr] = b1.y; Bs[sc+6][sr] = b1.z; Bs[sc+7][sr] = b1.w;
    __syncthreads();
    #pragma unroll
    for (int kk = 0; kk < 16; kk++){
      float a[8], b[8];
      *(float4*)(a)     = *(const float4*)&As[kk][tm];
      *(float4*)(a + 4) = *(const float4*)&As[kk][tm + 4];
      *(float4*)(b)     = *(const float4*)&Bs[kk][tn];
      *(float4*)(b + 4) = *(const float4*)&Bs[kk][tn + 4];
      #pragma unroll
      for (int i = 0; i < 8; i++)
        #pragma unroll
        for (int j = 0; j < 8; j++) acc[i][j] = fmaf(a[i], b[j], acc[i][j]);
    }
    __syncthreads();
  }
  #pragma unroll
  for (int i = 0; i < 8; i++){
    int row = m0 + tm + i;
    float* cp = C + (size_t)row * ldc + n0 + tn;
    if (resid){
      const float* rp = resid + (size_t)row * ldc + n0 + tn;
      #pragma unroll
      for (int j = 0; j < 8; j++) cp[j] = acc[i][j] + rp[j];
    } else {
      float4 v0, v1;
      v0.x = acc[i][0]; v0.y = acc[i][1]; v0.z = acc[i][2]; v0.w = acc[i][3];
      v1.x = acc[i][4]; v1.y = acc[i][5]; v1.z = acc[i][6]; v1.w = acc[i][7];
      *(float4*)cp = v0; *(float4*)(cp + 4) = v1;
    }
  }
}

// ---------------- RoPE tables (double precision to match np fp32 refs) -------
__global__ void k_rope_table(float* __restrict__ ctab, float* __restrict__ stab){
  int idx = blockIdx.x * 256 + threadIdx.x;  // 2048*16
  int pos = idx >> 4, kx = idx & 15;
  double inv = 1.0 / pow(10000.0, (double)kx / 16.0);
  float invf = (float)inv;
  float ang = (float)pos * invf;   // fp32 outer product, like the reference
  ctab[idx] = (float)cos((double)ang);
  stab[idx] = (float)sin((double)ang);
}

// interleaved rotary on q (cols 0..1023) and k (cols 1024..1279) of qkv
__global__ __launch_bounds__(256) void k_rope(float* __restrict__ qkv,
    const float* __restrict__ ctab, const float* __restrict__ stab){
  int idx = blockIdx.x * 256 + threadIdx.x;  // T_TOK * 640
  int t = idx / 640, p = idx - t * 640;
  int col, ph;
  if (p < 512){ int h = p >> 5; ph = p & 31; col = h * 64 + 2 * ph; }
  else { int p2 = p - 512; int h = p2 >> 5; ph = p2 & 31; col = 1024 + h * 64 + 2 * ph; }
  int pos = t & (S_LEN - 1);
  float c = ctab[pos * 16 + (ph & 15)];
  float s = stab[pos * 16 + (ph & 15)];
  float* base = qkv + (size_t)t * 1536 + col;
  float x1 = base[0], x2 = base[1];
  base[0] = x1 * c - x2 * s;
  base[1] = x1 * s + x2 * c;
}

// ---------------- flash attention fp32, causal, GQA ----------------
// 1 wave per 64 q-rows; thread owns one q row. Output overwrites q region.
__global__ __launch_bounds__(64) void k_attn(float* __restrict__ qkv){
  const int bx = blockIdx.x;   // q tile of 64
  const int h  = blockIdx.y;
  const int b  = blockIdx.z;
  const int tid = threadIdx.x;
  const int tok = b * S_LEN + bx * 64 + tid;
  __shared__ float Ks[64][68];
  __shared__ float Vs[64][68];
  float q[64], O[64];
  {
    const float* qp = qkv + (size_t)tok * 1536 + h * 64;
    #pragma unroll
    for (int c = 0; c < 16; c++){
      float4 v = *(const float4*)(qp + c * 4);
      q[c*4+0] = v.x * 0.125f; q[c*4+1] = v.y * 0.125f;
      q[c*4+2] = v.z * 0.125f; q[c*4+3] = v.w * 0.125f;
    }
  }
  #pragma unroll
  for (int d = 0; d < 64; d++) O[d] = 0.f;
  float m = -INFINITY, l = 0.f;
  const int kvh = h >> 2;
  const float* kbase = qkv + (size_t)(b * S_LEN) * 1536 + 1024 + kvh * 64;
  const float* vbase = kbase + 256;
  for (int kt = 0; kt <= bx; ++kt){
    #pragma unroll
    for (int i = 0; i < 16; i++){       // coalesced-ish staging: 4 rows x 16 lanes
      int r = i * 4 + (tid >> 4);
      int c = (tid & 15) << 2;
      size_t grow = (size_t)(kt * 64 + r) * 1536;
      *(float4*)&Ks[r][c] = *(const float4*)(kbase + grow + c);
      *(float4*)&Vs[r][c] = *(const float4*)(vbase + grow + c);
    }
    __syncthreads();
    const int jmax = (kt == bx) ? tid : 63;
    #pragma unroll
    for (int ch = 0; ch < 2; ++ch){
      const int jb = ch * 32;
      float s[32];
      #pragma unroll
      for (int jj = 0; jj < 32; jj += 2){
        float s0 = 0.f, s1 = 0.f;
        const float* kr0 = &Ks[jb + jj][0];
        const float* kr1 = &Ks[jb + jj + 1][0];
        #pragma unroll
        for (int c = 0; c < 16; c++){
          float4 k0 = *(const float4*)(kr0 + c * 4);
          float4 k1 = *(const float4*)(kr1 + c * 4);
          s0 = fmaf(q[c*4+0], k0.x, s0); s0 = fmaf(q[c*4+1], k0.y, s0);
          s0 = fmaf(q[c*4+2], k0.z, s0); s0 = fmaf(q[c*4+3], k0.w, s0);
          s1 = fmaf(q[c*4+0], k1.x, s1); s1 = fmaf(q[c*4+1], k1.y, s1);
          s1 = fmaf(q[c*4+2], k1.z, s1); s1 = fmaf(q[c*4+3], k1.w, s1);
        }
        s[jj] = s0; s[jj + 1] = s1;
      }
      float tmax = -INFINITY;
      #pragma unroll
      for (int jj = 0; jj < 32; jj++)
        if (jb + jj <= jmax) tmax = fmaxf(tmax, s[jj]);
      float mn = fmaxf(m, tmax);
      float corr = expf(m - mn);     // m=-inf -> 0
      l *= corr;
      #pragma unroll
      for (int d = 0; d < 64; d++) O[d] *= corr;
      float ps = 0.f;
      #pragma unroll
      for (int jj = 0; jj < 32; jj++){
        float p = (jb + jj <= jmax) ? expf(s[jj] - mn) : 0.f;
        s[jj] = p; ps += p;
      }
      l += ps;
      #pragma unroll
      for (int jj = 0; jj < 32; jj++){
        float p = s[jj];
        const float* vr = &Vs[jb + jj][0];
        #pragma unroll
        for (int c = 0; c < 16; c++){
          float4 v4 = *(const float4*)(vr + c * 4);
          O[c*4+0] = fmaf(p, v4.x, O[c*4+0]);
          O[c*4+1] = fmaf(p, v4.y, O[c*4+1]);
          O[c*4+2] = fmaf(p, v4.z, O[c*4+2]);
          O[c*4+3] = fmaf(p, v4.w, O[c*4+3]);
        }
      }
      m = mn;
    }
    __syncthreads();
  }
  float inv_l = 1.f / l;
  float* op = qkv + (size_t)tok * 1536 + h * 64;
  #pragma unroll
  for (int c = 0; c < 16; c++){
    float4 o4;
    o4.x = O[c*4+0] * inv_l; o4.y = O[c*4+1] * inv_l;
    o4.z = O[c*4+2] * inv_l; o4.w = O[c*4+3] * inv_l;
    *(float4*)(op + c * 4) = o4;
  }
}

// ---------------- router: fp32 logits, softmax, top-2 (lower index on ties) --
__global__ __launch_bounds__(64) void k_router(const float* __restrict__ norm2,
    const float* __restrict__ rw, float* __restrict__ p_all,
    int2* __restrict__ idx2, float2* __restrict__ tokw){
  const int t = blockIdx.x;
  const int lane = threadIdx.x;
  const float* xr = norm2 + (size_t)t * D_MODEL;
  float part[8];
  #pragma unroll
  for (int e = 0; e < 8; e++) part[e] = 0.f;
  #pragma unroll
  for (int c = 0; c < 4; c++){
    float4 xv = *(const float4*)(xr + c * 256 + lane * 4);
    #pragma unroll
    for (int e = 0; e < 8; e++){
      float4 wv = *(const float4*)(rw + e * D_MODEL + c * 256 + lane * 4);
      part[e] += xv.x*wv.x + xv.y*wv.y + xv.z*wv.z + xv.w*wv.w;
    }
  }
  #pragma unroll
  for (int e = 0; e < 8; e++){
    float v = part[e];
    #pragma unroll
    for (int msk = 1; msk < 64; msk <<= 1) v += __shfl_xor(v, msk);
    part[e] = v;
  }
  if (lane == 0){
    float mx = part[0];
    #pragma unroll
    for (int e = 1; e < 8; e++) mx = fmaxf(mx, part[e]);
    float p[8]; float sum = 0.f;
    #pragma unroll
    for (int e = 0; e < 8; e++){ p[e] = expf(part[e] - mx); sum += p[e]; }
    float inv = 1.f / sum;
    #pragma unroll
    for (int e = 0; e < 8; e++) p[e] *= inv;
    int i1 = 0;
    for (int e = 1; e < 8; e++) if (p[e] > p[i1]) i1 = e;
    int i2 = (i1 == 0) ? 1 : 0;
    for (int e = 0; e < 8; e++){ if (e != i1 && p[e] > p[i2]) i2 = e; }
    float denom = p[i1] + p[i2];
    float2 w; w.x = p[i1] / denom; w.y = p[i2] / denom;
    #pragma unroll
    for (int e = 0; e < 8; e++) p_all[t * 8 + e] = p[e];
    idx2[t] = make_int2(i1, i2);
    tokw[t] = w;
  }
}

// ---------------- finalize: counts, offsets, aux loss, tpe outputs -----------
__global__ __launch_bounds__(256) void k_finalize(const float* __restrict__ p_all,
    const int2* __restrict__ idx2, float* __restrict__ out,
    int* __restrict__ cnt, int* __restrict__ offs, int* __restrict__ cursor){
  __shared__ int sc[8];
  __shared__ float sp[8];
  const int tid = threadIdx.x;
  if (tid < 8){ sc[tid] = 0; sp[tid] = 0.f; }
  __syncthreads();
  int cl[8]; float pl[8];
  #pragma unroll
  for (int e = 0; e < 8; e++){ cl[e] = 0; pl[e] = 0.f; }
  for (int t = tid; t < T_TOK; t += 256){
    int2 id = idx2[t];
    cl[id.x]++; cl[id.y]++;
    #pragma unroll
    for (int e = 0; e < 8; e++) pl[e] += p_all[t * 8 + e];
  }
  #pragma unroll
  for (int e = 0; e < 8; e++){ atomicAdd(&sc[e], cl[e]); atomicAdd(&sp[e], pl[e]); }
  __syncthreads();
  if (tid == 0){
    float aux = 0.f; int off = 0;
    for (int e = 0; e < 8; e++){
      out[4194305 + e] = (float)sc[e];
      aux += ((float)sc[e] / 8192.0f) * (sp[e] / 4096.0f);
      offs[e] = off; cnt[e] = sc[e]; cursor[e] = 0; off += sc[e];
    }
    out[4194304] = aux * 8.0f;
  }
}

__global__ __launch_bounds__(256) void k_scatter(const int2* __restrict__ idx2,
    const float2* __restrict__ tokw, const int* __restrict__ offs,
    int* __restrict__ cursor, int* __restrict__ perm, float* __restrict__ wgt){
  int t = blockIdx.x * 256 + threadIdx.x;
  if (t >= T_TOK) return;
  int2 id = idx2[t]; float2 w = tokw[t];
  int p1 = atomicAdd(&cursor[id.x], 1);
  perm[offs[id.x] + p1] = t; wgt[offs[id.x] + p1] = w.x;
  int p2 = atomicAdd(&cursor[id.y], 1);
  perm[offs[id.y] + p2] = t; wgt[offs[id.y] + p2] = w.y;
}

// ---------------- MoE phase A: H = silu(X Wg^T) * (X Wu^T), bf16 MFMA --------
// tile 64(assign rows) x 128(ff), BK=32, 4 waves: wave = (wm in 2) x (wn in 2), 32x64 each
__global__ __launch_bounds__(256) void k_moe_a(
    const float* __restrict__ norm2, const float* __restrict__ Wg, const float* __restrict__ Wu,
    const int* __restrict__ cnt, const int* __restrict__ offs,
    const int* __restrict__ perm, unsigned short* __restrict__ Hbuf)
{
  int rem = blockIdx.x, e = -1, m0 = 0;
  #pragma unroll
  for (int i = 0; i < 8; i++){
    int nt = (cnt[i] + 63) >> 6;
    if (e < 0 && rem < nt){ e = i; m0 = rem << 6; }
    if (e < 0) rem -= nt;
  }
  if (e < 0) return;
  const int n0 = blockIdx.y * 128;
  const int ne = cnt[e];
  const int seg0 = offs[e];
  __shared__ unsigned short As[64][40];
  __shared__ unsigned short Bg[128][40];
  __shared__ unsigned short Bu[128][40];
  const int tid = threadIdx.x;
  const int lane = tid & 63, w = tid >> 6;
  const int wm = w >> 1, wn = w & 1;
  f32x4 accg[2][4], accu[2][4];
  #pragma unroll
  for (int i = 0; i < 2; i++)
    #pragma unroll
    for (int j = 0; j < 4; j++){
      accg[i][j] = (f32x4){0.f,0.f,0.f,0.f};
      accu[i][j] = (f32x4){0.f,0.f,0.f,0.f};
    }
  // A staging: threads 0..127 -> (row, 16-col half)
  const int ar = tid >> 1, ah = (tid & 1) << 4;
  bool aval = false; const float* asrc = norm2;
  if (tid < 128){
    aval = (m0 + ar < ne);
    int token = aval ? perm[seg0 + m0 + ar] : 0;
    asrc = norm2 + (size_t)token * D_MODEL + ah;
  }
  // B staging: thread -> one of 256 (matrix, row) pairs, 32 cols each
  const int br = tid & 127;
  const float* bsrc = ((tid >> 7) ? Wu : Wg) + (size_t)e * DFF * D_MODEL
                      + (size_t)(n0 + br) * D_MODEL;
  unsigned short (*Bt)[40] = (tid >> 7) ? Bu : Bg;
  const int fr = lane & 15, fk = (lane >> 4) << 3;
  for (int k0 = 0; k0 < D_MODEL; k0 += 32){
    if (tid < 128){
      u16x8 w0 = (u16x8){0,0,0,0,0,0,0,0}, w1 = w0;
      if (aval){
        float4 f0 = *(const float4*)(asrc + k0);
        float4 f1 = *(const float4*)(asrc + k0 + 4);
        float4 f2 = *(const float4*)(asrc + k0 + 8);
        float4 f3 = *(const float4*)(asrc + k0 + 12);
        w0[0]=f2bf(f0.x); w0[1]=f2bf(f0.y); w0[2]=f2bf(f0.z); w0[3]=f2bf(f0.w);
        w0[4]=f2bf(f1.x); w0[5]=f2bf(f1.y); w0[6]=f2bf(f1.z); w0[7]=f2bf(f1.w);
        w1[0]=f2bf(f2.x); w1[1]=f2bf(f2.y); w1[2]=f2bf(f2.z); w1[3]=f2bf(f2.w);
        w1[4]=f2bf(f3.x); w1[5]=f2bf(f3.y); w1[6]=f2bf(f3.z); w1[7]=f2bf(f3.w);
      }
      *(u16x8*)&As[ar][ah] = w0;
      *(u16x8*)&As[ar][ah + 8] = w1;
    }
    {
      float4 f0 = *(const float4*)(bsrc + k0);
      float4 f1 = *(const float4*)(bsrc + k0 + 4);
      float4 f2 = *(const float4*)(bsrc + k0 + 8);
      float4 f3 = *(const float4*)(bsrc + k0 + 12);
      float4 f4 = *(const float4*)(bsrc + k0 + 16);
      float4 f5 = *(const float4*)(bsrc + k0 + 20);
      float4 f6 = *(const float4*)(bsrc + k0 + 24);
      float4 f7 = *(const float4*)(bsrc + k0 + 28);
      u16x8 w0, w1, w2, w3;
      w0[0]=f2bf(f0.x); w0[1]=f2bf(f0.y); w0[2]=f2bf(f0.z); w0[3]=f2bf(f0.w);
      w0[4]=f2bf(f1.x); w0[5]=f2bf(f1.y); w0[6]=f2bf(f1.z); w0[7]=f2bf(f1.w);
      w1[0]=f2bf(f2.x); w1[1]=f2bf(f2.y); w1[2]=f2bf(f2.z); w1[3]=f2bf(f2.w);
      w1[4]=f2bf(f3.x); w1[5]=f2bf(f3.y); w1[6]=f2bf(f3.z); w1[7]=f2bf(f3.w);
      w2[0]=f2bf(f4.x); w2[1]=f2bf(f4.y); w2[2]=f2bf(f4.z); w2[3]=f2bf(f4.w);
      w2[4]=f2bf(f5.x); w2[5]=f2bf(f5.y); w2[6]=f2bf(f5.z); w2[7]=f2bf(f5.w);
      w3[0]=f2bf(f6.x); w3[1]=f2bf(f6.y); w3[2]=f2bf(f6.z); w3[3]=f2bf(f6.w);
      w3[4]=f2bf(f7.x); w3[5]=f2bf(f7.y); w3[6]=f2bf(f7.z); w3[7]=f2bf(f7.w);
      *(u16x8*)&Bt[br][0]  = w0; *(u16x8*)&Bt[br][8]  = w1;
      *(u16x8*)&Bt[br][16] = w2; *(u16x8*)&Bt[br][24] = w3;
    }
    __syncthreads();
    bf16x8 af0 = *(const bf16x8*)&As[wm*32 + fr][fk];
    bf16x8 af1 = *(const bf16x8*)&As[wm*32 + 16 + fr][fk];
    #pragma unroll
    for (int fn = 0; fn < 4; fn++){
      bf16x8 bg = *(const bf16x8*)&Bg[wn*64 + fn*16 + fr][fk];
      bf16x8 bu = *(const bf16x8*)&Bu[wn*64 + fn*16 + fr][fk];
      accg[0][fn] = __builtin_amdgcn_mfma_f32_16x16x32_bf16(af0, bg, accg[0][fn], 0, 0, 0);
      accg[1][fn] = __builtin_amdgcn_mfma_f32_16x16x32_bf16(af1, bg, accg[1][fn], 0, 0, 0);
      accu[0][fn] = __builtin_amdgcn_mfma_f32_16x16x32_bf16(af0, bu, accu[0][fn], 0, 0, 0);
      accu[1][fn] = __builtin_amdgcn_mfma_f32_16x16x32_bf16(af1, bu, accu[1][fn], 0, 0, 0);
    }
    __syncthreads();
  }
  const int r0 = (lane >> 4) << 2, cix = lane & 15;
  #pragma unroll
  for (int fm = 0; fm < 2; fm++)
    #pragma unroll
    for (int fn = 0; fn < 4; fn++)
      #pragma unroll
      for (int reg = 0; reg < 4; reg++){
        int ml = wm*32 + fm*16 + r0 + reg;
        if (m0 + ml < ne){
          int nl = wn*64 + fn*16 + cix;
          float g = accg[fm][fn][reg];
          float u = accu[fm][fn][reg];
          float h = g / (1.f + __expf(-g)) * u;
          Hbuf[(size_t)(seg0 + m0 + ml) * DFF + n0 + nl] = f2bf(h);
        }
      }
}

// ---------------- MoE phase B: Y = H Wd^T, weighted atomic scatter-add -------
__global__ __launch_bounds__(256) void k_moe_b(
    const unsigned short* __restrict__ Hbuf, const float* __restrict__ Wd,
    const int* __restrict__ cnt, const int* __restrict__ offs,
    const int* __restrict__ perm, const float* __restrict__ wgt,
    float* __restrict__ outx)
{
  int rem = blockIdx.x, e = -1, m0 = 0;
  #pragma unroll
  for (int i = 0; i < 8; i++){
    int nt = (cnt[i] + 63) >> 6;
    if (e < 0 && rem < nt){ e = i; m0 = rem << 6; }
    if (e < 0) rem -= nt;
  }
  if (e < 0) return;
  const int n0 = blockIdx.y * 128;
  const int ne = cnt[e];
  const int seg0 = offs[e];
  __shared__ unsigned short As[64][40];
  __shared__ unsigned short Bs[128][40];
  const int tid = threadIdx.x;
  const int lane = tid & 63, w = tid >> 6;
  const int wm = w >> 1, wn = w & 1;
  f32x4 acc[2][4];
  #pragma unroll
  for (int i = 0; i < 2; i++)
    #pragma unroll
    for (int j = 0; j < 4; j++) acc[i][j] = (f32x4){0.f,0.f,0.f,0.f};
  const int ar = tid >> 1, ah = (tid & 1) << 4;
  const bool aval = (tid < 128) && (m0 + ar < ne);
  const unsigned short* asrc = aval ? (Hbuf + (size_t)(seg0 + m0 + ar) * DFF + ah) : Hbuf;
  const int br = tid >> 1, bh = (tid & 1) << 4;
  const float* bsrc = Wd + (size_t)e * D_MODEL * DFF + (size_t)(n0 + br) * DFF + bh;
  const int fr = lane & 15, fk = (lane >> 4) << 3;
  for (int k0 = 0; k0 < DFF; k0 += 32){
    if (tid < 128){
      u16x8 w0 = (u16x8){0,0,0,0,0,0,0,0}, w1 = w0;
      if (aval){
        w0 = *(const u16x8*)(asrc + k0);
        w1 = *(const u16x8*)(asrc + k0 + 8);
      }
      *(u16x8*)&As[ar][ah] = w0;
      *(u16x8*)&As[ar][ah + 8] = w1;
    }
    {
      float4 f0 = *(const float4*)(bsrc + k0);
      float4 f1 = *(const float4*)(bsrc + k0 + 4);
      float4 f2 = *(const float4*)(bsrc + k0 + 8);
      float4 f3 = *(const float4*)(bsrc + k0 + 12);
      u16x8 w0, w1;
      w0[0]=f2bf(f0.x); w0[1]=f2bf(f0.y); w0[2]=f2bf(f0.z); w0[3]=f2bf(f0.w);
      w0[4]=f2bf(f1.x); w0[5]=f2bf(f1.y); w0[6]=f2bf(f1.z); w0[7]=f2bf(f1.w);
      w1[0]=f2bf(f2.x); w1[1]=f2bf(f2.y); w1[2]=f2bf(f2.z); w1[3]=f2bf(f2.w);
      w1[4]=f2bf(f3.x); w1[5]=f2bf(f3.y); w1[6]=f2bf(f3.z); w1[7]=f2bf(f3.w);
      *(u16x8*)&Bs[br][bh] = w0;
      *(u16x8*)&Bs[br][bh + 8] = w1;
    }
    __syncthreads();
    bf16x8 af0 = *(const bf16x8*)&As[wm*32 + fr][fk];
    bf16x8 af1 = *(const bf16x8*)&As[wm*32 + 16 + fr][fk];
    #pragma unroll
    for (int fn = 0; fn < 4; fn++){
      bf16x8 bf = *(const bf16x8*)&Bs[wn*64 + fn*16 + fr][fk];
      acc[0][fn] = __builtin_amdgcn_mfma_f32_16x16x32_bf16(af0, bf, acc[0][fn], 0, 0, 0);
      acc[1][fn] = __builtin_amdgcn_mfma_f32_16x16x32_bf16(af1, bf, acc[1][fn], 0, 0, 0);
    }
    __syncthreads();
  }
  const int r0 = (lane >> 4) << 2, cix = lane & 15;
  #pragma unroll
  for (int fm = 0; fm < 2; fm++)
    #pragma unroll
    for (int reg = 0; reg < 4; reg++){
      int ml = wm*32 + fm*16 + r0 + reg;
      if (m0 + ml < ne){
        int g = seg0 + m0 + ml;
        int token = perm[g];
        float wwt = wgt[g];
        #pragma unroll
        for (int fn = 0; fn < 4; fn++){
          int nl = wn*64 + fn*16 + cix;
          atomicAdd(&outx[(size_t)token * D_MODEL + n0 + nl], wwt * acc[fm][fn][reg]);
        }
      }
    }
}

// ---------------- launch ----------------
extern "C" void kernel_launch(void* const* d_in, const int* in_sizes, int n_in,
                              void* d_out, int out_size, void* d_ws, size_t ws_size,
                              hipStream_t stream)
{
  const float* x   = (const float*)d_in[0];
  const float* wq  = (const float*)d_in[1];
  const float* wk  = (const float*)d_in[2];
  const float* wv  = (const float*)d_in[3];
  const float* wo  = (const float*)d_in[4];
  const float* anw = (const float*)d_in[5];
  const float* fnw = (const float*)d_in[6];
  const float* rw  = (const float*)d_in[7];
  const float* Wg  = (const float*)d_in[8];
  const float* Wu  = (const float*)d_in[9];
  const float* Wd  = (const float*)d_in[10];
  float* out = (float*)d_out;

  char* ws = (char*)d_ws;
  size_t off = 0;
  auto alloc = [&](size_t bytes){ char* p = ws + off; off += (bytes + 255) & ~(size_t)255; return p; };
  float* norm            = (float*)alloc((size_t)T_TOK * D_MODEL * 4);   // 16.8 MB
  float* qkv             = (float*)alloc((size_t)T_TOK * 1536 * 4);      // 25.2 MB
  unsigned short* Hbuf   = (unsigned short*)alloc((size_t)8192 * DFF * 2); // 33.6 MB
  float* ctab            = (float*)alloc(2048 * 16 * 4);
  float* stab            = (float*)alloc(2048 * 16 * 4);
  float* p_all           = (float*)alloc((size_t)T_TOK * 8 * 4);
  int2* idx2             = (int2*)alloc((size_t)T_TOK * 8);
  float2* tokw           = (float2*)alloc((size_t)T_TOK * 8);
  int* cnt               = (int*)alloc(32);
  int* offs              = (int*)alloc(32);
  int* cursor            = (int*)alloc(32);
  int* perm              = (int*)alloc(8192 * 4);
  float* wgt             = (float*)alloc(8192 * 4);

  k_rope_table<<<128, 256, 0, stream>>>(ctab, stab);
  k_rmsnorm<<<T_TOK, 256, 0, stream>>>(x, anw, norm);
  // qkv = norm1 @ [wq;wk;wv]^T   (N=1536: wq rows 0..1023, wk 1024..1279, wv 1280..1535)
  k_gemm_f32<<<dim3(12, 32), 256, 0, stream>>>(norm, D_MODEL, wq, wk, wv, 1024, 1280,
                                               qkv, 1536, nullptr, D_MODEL);
  k_rope<<<(T_TOK * 640) / 256, 256, 0, stream>>>(qkv, ctab, stab);
  k_attn<<<dim3(32, 16, 2), 64, 0, stream>>>(qkv);
  // x1 = attn_out @ wo^T + x  -> d_out
  k_gemm_f32<<<dim3(8, 32), 256, 0, stream>>>(qkv, 1536, wo, nullptr, nullptr, 1 << 29, 1 << 29,
                                              out, D_MODEL, x, D_MODEL);
  k_rmsnorm<<<T_TOK, 256, 0, stream>>>(out, fnw, norm);
  k_router<<<T_TOK, 64, 0, stream>>>(norm, rw, p_all, idx2, tokw);
  k_finalize<<<1, 256, 0, stream>>>(p_all, idx2, out, cnt, offs, cursor);
  k_scatter<<<16, 256, 0, stream>>>(idx2, tokw, offs, cursor, perm, wgt);
  k_moe_a<<<dim3(136, 16), 256, 0, stream>>>(norm, Wg, Wu, cnt, offs, perm, Hbuf);
  k_moe_b<<<dim3(136, 8), 256, 0, stream>>>(Hbuf, Wd, cnt, offs, perm, wgt, out);
}

// Round 5
// 2613.310 us; speedup vs baseline: 1.1469x; 1.1469x over previous
//
#include <hip/hip_runtime.h>
#include <hip/hip_bf16.h>
#include <math.h>

typedef __attribute__((ext_vector_type(4))) float f32x4;
typedef __attribute__((ext_vector_type(8))) short bf16x8;
typedef __attribute__((ext_vector_type(8))) unsigned short u16x8;

#define D_MODEL 1024
#define DFF 2048
#define S_LEN 2048
#define T_TOK 4096
#define NEXP 8

__device__ __forceinline__ unsigned short f2bf(float f){
  union { float f; unsigned u; } v; v.f = f;
  unsigned u = v.u;
  u += 0x7fffu + ((u >> 16) & 1u);
  return (unsigned short)(u >> 16);
}

// ---------------- RMSNorm: one block per token ----------------
__global__ __launch_bounds__(256) void k_rmsnorm(const float* __restrict__ x,
    const float* __restrict__ w, float* __restrict__ out){
  const int t = blockIdx.x;
  const int tid = threadIdx.x;
  const float* row = x + (size_t)t * D_MODEL;
  float4 v = *(const float4*)(row + tid * 4);
  float ss = v.x*v.x + v.y*v.y + v.z*v.z + v.w*v.w;
  #pragma unroll
  for (int m = 1; m < 64; m <<= 1) ss += __shfl_xor(ss, m);
  __shared__ float red[4];
  if ((tid & 63) == 0) red[tid >> 6] = ss;
  __syncthreads();
  float tot = red[0] + red[1] + red[2] + red[3];
  float mean = tot * (1.0f / D_MODEL);
  float r = (float)(1.0 / sqrt((double)mean + 1e-6));
  float4 wv = *(const float4*)(w + tid * 4);
  float4 o;
  o.x = v.x * r * wv.x; o.y = v.y * r * wv.y;
  o.z = v.z * r * wv.z; o.w = v.w * r * wv.w;
  *(float4*)(out + (size_t)t * D_MODEL + tid * 4) = o;
}

// ---------------- fp32 GEMM: C[m,n] = sum_k A[m,k]*B[n,k] (+resid) ----------------
__global__ __launch_bounds__(256) void k_gemm_f32(
    const float* __restrict__ A, int lda,
    const float* __restrict__ B0, const float* __restrict__ B1, const float* __restrict__ B2,
    int nb1, int nb2,
    float* __restrict__ C, int ldc,
    const float* __restrict__ resid, int K)
{
  __shared__ float As[16][132];
  __shared__ float Bs[16][132];
  const int n0 = blockIdx.x * 128, m0 = blockIdx.y * 128;
  const float* Bp; int nsub;
  if (B2 && n0 >= nb2)      { Bp = B2; nsub = n0 - nb2; }
  else if (B1 && n0 >= nb1) { Bp = B1; nsub = n0 - nb1; }
  else                      { Bp = B0; nsub = n0; }
  const int tid = threadIdx.x;
  const int sr = tid >> 1, sc = (tid & 1) << 3;
  const float* ap = A + (size_t)(m0 + sr) * lda + sc;
  const float* bp = Bp + (size_t)(nsub + sr) * K + sc;
  float acc[8][8];
  #pragma unroll
  for (int i = 0; i < 8; i++)
    #pragma unroll
    for (int j = 0; j < 8; j++) acc[i][j] = 0.f;
  const int tm = (tid >> 4) << 3, tn = (tid & 15) << 3;
  for (int k0 = 0; k0 < K; k0 += 16){
    float4 a0 = *(const float4*)(ap + k0);
    float4 a1 = *(const float4*)(ap + k0 + 4);
    float4 b0 = *(const float4*)(bp + k0);
    float4 b1 = *(const float4*)(bp + k0 + 4);
    As[sc+0][sr] = a0.x; As[sc+1][sr] = a0.y; As[sc+2][sr] = a0.z; As[sc+3][sr] = a0.w;
    As[sc+4][sr] = a1.x; As[sc+5][sr] = a1.y; As[sc+6][sr] = a1.z; As[sc+7][sr] = a1.w;
    Bs[sc+0][sr] = b0.x; Bs[sc+1][sr] = b0.y; Bs[sc+2][sr] = b0.z; Bs[sc+3][sr] = b0.w;
    Bs[sc+4][sr] = b1.x; Bs[sc+5][sr] = b1.y; Bs[sc+6][sr] = b1.z; Bs[sc+7][sr] = b1.w;
    __syncthreads();
    #pragma unroll
    for (int kk = 0; kk < 16; kk++){
      float a[8], b[8];
      *(float4*)(a)     = *(const float4*)&As[kk][tm];
      *(float4*)(a + 4) = *(const float4*)&As[kk][tm + 4];
      *(float4*)(b)     = *(const float4*)&Bs[kk][tn];
      *(float4*)(b + 4) = *(const float4*)&Bs[kk][tn + 4];
      #pragma unroll
      for (int i = 0; i < 8; i++)
        #pragma unroll
        for (int j = 0; j < 8; j++) acc[i][j] = fmaf(a[i], b[j], acc[i][j]);
    }
    __syncthreads();
  }
  #pragma unroll
  for (int i = 0; i < 8; i++){
    int row = m0 + tm + i;
    float* cp = C + (size_t)row * ldc + n0 + tn;
    if (resid){
      const float* rp = resid + (size_t)row * ldc + n0 + tn;
      #pragma unroll
      for (int j = 0; j < 8; j++) cp[j] = acc[i][j] + rp[j];
    } else {
      float4 v0, v1;
      v0.x = acc[i][0]; v0.y = acc[i][1]; v0.z = acc[i][2]; v0.w = acc[i][3];
      v1.x = acc[i][4]; v1.y = acc[i][5]; v1.z = acc[i][6]; v1.w = acc[i][7];
      *(float4*)cp = v0; *(float4*)(cp + 4) = v1;
    }
  }
}

// ---------------- RoPE tables (double precision) -------
__global__ void k_rope_table(float* __restrict__ ctab, float* __restrict__ stab){
  int idx = blockIdx.x * 256 + threadIdx.x;  // 2048*16
  int pos = idx >> 4, kx = idx & 15;
  double inv = 1.0 / pow(10000.0, (double)kx / 16.0);
  float invf = (float)inv;
  float ang = (float)pos * invf;   // fp32 outer product, like the reference
  ctab[idx] = (float)cos((double)ang);
  stab[idx] = (float)sin((double)ang);
}

// interleaved rotary on q (cols 0..1023) and k (cols 1024..1279) of qkv
__global__ __launch_bounds__(256) void k_rope(float* __restrict__ qkv,
    const float* __restrict__ ctab, const float* __restrict__ stab){
  int idx = blockIdx.x * 256 + threadIdx.x;  // T_TOK * 640
  int t = idx / 640, p = idx - t * 640;
  int col, ph;
  if (p < 512){ int h = p >> 5; ph = p & 31; col = h * 64 + 2 * ph; }
  else { int p2 = p - 512; int h = p2 >> 5; ph = p2 & 31; col = 1024 + h * 64 + 2 * ph; }
  int pos = t & (S_LEN - 1);
  float c = ctab[pos * 16 + (ph & 15)];
  float s = stab[pos * 16 + (ph & 15)];
  float* base = qkv + (size_t)t * 1536 + col;
  float x1 = base[0], x2 = base[1];
  base[0] = x1 * c - x2 * s;
  base[1] = x1 * s + x2 * c;
}

// ---------------- flash attention fp32, causal, GQA — KV-split partials -----
// One wave per (q-tile 64, head, batch, kv-chunk C). Thread owns one q row.
// K/V row addresses are wave-uniform -> scalar loads, no LDS.
__global__ __launch_bounds__(64) void k_attn_part(const float* __restrict__ qkv,
    float* __restrict__ Opart, float* __restrict__ ml, int C){
  const int bx = blockIdx.x, h = blockIdx.y;
  const int nc_max = gridDim.z >> 1;
  const int b = blockIdx.z / nc_max;
  const int c = blockIdx.z - b * nc_max;
  const int L = (bx + 1) * 64;
  const int kv0 = c * C;
  if (kv0 >= L) return;
  const int kv1 = min(kv0 + C, L);
  const int tid = threadIdx.x;
  const int qrow = bx * 64 + tid;
  const float* qp = qkv + ((size_t)(b * S_LEN + qrow)) * 1536 + h * 64;
  float q[64];
  #pragma unroll
  for (int d4 = 0; d4 < 16; d4++){
    float4 v = *(const float4*)(qp + d4 * 4);
    q[d4*4+0] = v.x * 0.125f; q[d4*4+1] = v.y * 0.125f;
    q[d4*4+2] = v.z * 0.125f; q[d4*4+3] = v.w * 0.125f;
  }
  float O[64];
  #pragma unroll
  for (int d = 0; d < 64; d++) O[d] = 0.f;
  float m = -INFINITY, l = 0.f;
  const float* kb = qkv + (size_t)(b * S_LEN) * 1536 + 1024 + (h >> 2) * 64;
  const float* vb = kb + 256;
  for (int j0 = kv0; j0 < kv1; j0 += 32){
    float s[32];
    #pragma unroll
    for (int jj = 0; jj < 32; jj++){
      const float* kr = kb + (size_t)(j0 + jj) * 1536;
      float a0 = 0.f, a1 = 0.f;
      #pragma unroll
      for (int d4 = 0; d4 < 8; d4++){
        float4 k0 = *(const float4*)(kr + d4 * 8);
        float4 k1 = *(const float4*)(kr + d4 * 8 + 4);
        a0 = fmaf(q[d4*8+0], k0.x, a0); a0 = fmaf(q[d4*8+1], k0.y, a0);
        a0 = fmaf(q[d4*8+2], k0.z, a0); a0 = fmaf(q[d4*8+3], k0.w, a0);
        a1 = fmaf(q[d4*8+4], k1.x, a1); a1 = fmaf(q[d4*8+5], k1.y, a1);
        a1 = fmaf(q[d4*8+6], k1.z, a1); a1 = fmaf(q[d4*8+7], k1.w, a1);
      }
      s[jj] = a0 + a1;
    }
    const int jm = qrow - j0;          // lanes mask rows beyond the diagonal
    float tmax = -INFINITY;
    #pragma unroll
    for (int jj = 0; jj < 32; jj++)
      tmax = fmaxf(tmax, (jj <= jm) ? s[jj] : -INFINITY);
    float mn = fmaxf(m, tmax);
    float corr = __expf(m - mn);       // m=-inf -> 0
    l *= corr;
    #pragma unroll
    for (int d = 0; d < 64; d++) O[d] *= corr;
    float ps = 0.f;
    #pragma unroll
    for (int jj = 0; jj < 32; jj++){
      float p = (jj <= jm) ? __expf(s[jj] - mn) : 0.f;
      s[jj] = p; ps += p;
    }
    l += ps;
    #pragma unroll
    for (int jj = 0; jj < 32; jj++){
      const float p = s[jj];
      const float* vr = vb + (size_t)(j0 + jj) * 1536;
      #pragma unroll
      for (int d4 = 0; d4 < 16; d4++){
        float4 v4 = *(const float4*)(vr + d4 * 4);
        O[d4*4+0] = fmaf(p, v4.x, O[d4*4+0]);
        O[d4*4+1] = fmaf(p, v4.y, O[d4*4+1]);
        O[d4*4+2] = fmaf(p, v4.z, O[d4*4+2]);
        O[d4*4+3] = fmaf(p, v4.w, O[d4*4+3]);
      }
    }
    m = mn;
  }
  const int uid = ((b * nc_max + c) * 16 + h) * 32 + bx;
  float* op = Opart + (size_t)uid * 4096;
  #pragma unroll
  for (int d4 = 0; d4 < 16; d4++){
    float4 o4;
    o4.x = O[d4*4+0]; o4.y = O[d4*4+1]; o4.z = O[d4*4+2]; o4.w = O[d4*4+3];
    *(float4*)(op + d4 * 256 + tid * 4) = o4;   // coalesced per d4
  }
  ml[(size_t)uid * 128 + tid] = m;
  ml[(size_t)uid * 128 + 64 + tid] = l;
}

// combine <=nc_max partials per (q-tile, head, batch); write into qkv q-region
__global__ __launch_bounds__(64) void k_attn_comb(const float* __restrict__ Opart,
    const float* __restrict__ ml, float* __restrict__ qkv, int C){
  const int bx = blockIdx.x, h = blockIdx.y, b = blockIdx.z;
  const int tid = threadIdx.x;
  const int L = (bx + 1) * 64;
  const int NC = (L + C - 1) / C;
  const int nc_max = (S_LEN + C - 1) / C;
  float m = -INFINITY;
  for (int c = 0; c < NC; c++){
    int uid = ((b * nc_max + c) * 16 + h) * 32 + bx;
    m = fmaxf(m, ml[(size_t)uid * 128 + tid]);
  }
  float O[64];
  #pragma unroll
  for (int d = 0; d < 64; d++) O[d] = 0.f;
  float l = 0.f;
  for (int c = 0; c < NC; c++){
    int uid = ((b * nc_max + c) * 16 + h) * 32 + bx;
    float w = __expf(ml[(size_t)uid * 128 + tid] - m);
    l = fmaf(ml[(size_t)uid * 128 + 64 + tid], w, l);
    const float* op = Opart + (size_t)uid * 4096;
    #pragma unroll
    for (int d4 = 0; d4 < 16; d4++){
      float4 v = *(const float4*)(op + d4 * 256 + tid * 4);
      O[d4*4+0] = fmaf(w, v.x, O[d4*4+0]);
      O[d4*4+1] = fmaf(w, v.y, O[d4*4+1]);
      O[d4*4+2] = fmaf(w, v.z, O[d4*4+2]);
      O[d4*4+3] = fmaf(w, v.w, O[d4*4+3]);
    }
  }
  float inv = 1.f / l;
  float* qp = qkv + ((size_t)(b * S_LEN + bx * 64 + tid)) * 1536 + h * 64;
  #pragma unroll
  for (int d4 = 0; d4 < 16; d4++){
    float4 o4;
    o4.x = O[d4*4+0] * inv; o4.y = O[d4*4+1] * inv;
    o4.z = O[d4*4+2] * inv; o4.w = O[d4*4+3] * inv;
    *(float4*)(qp + d4 * 4) = o4;
  }
}

// ---------------- router: fp32 logits, softmax, top-2 (lower index on ties) --
__global__ __launch_bounds__(64) void k_router(const float* __restrict__ norm2,
    const float* __restrict__ rw, float* __restrict__ p_all,
    int2* __restrict__ idx2, float2* __restrict__ tokw){
  const int t = blockIdx.x;
  const int lane = threadIdx.x;
  const float* xr = norm2 + (size_t)t * D_MODEL;
  float part[8];
  #pragma unroll
  for (int e = 0; e < 8; e++) part[e] = 0.f;
  #pragma unroll
  for (int c = 0; c < 4; c++){
    float4 xv = *(const float4*)(xr + c * 256 + lane * 4);
    #pragma unroll
    for (int e = 0; e < 8; e++){
      float4 wv = *(const float4*)(rw + e * D_MODEL + c * 256 + lane * 4);
      part[e] += xv.x*wv.x + xv.y*wv.y + xv.z*wv.z + xv.w*wv.w;
    }
  }
  #pragma unroll
  for (int e = 0; e < 8; e++){
    float v = part[e];
    #pragma unroll
    for (int msk = 1; msk < 64; msk <<= 1) v += __shfl_xor(v, msk);
    part[e] = v;
  }
  if (lane == 0){
    float mx = part[0];
    #pragma unroll
    for (int e = 1; e < 8; e++) mx = fmaxf(mx, part[e]);
    float p[8]; float sum = 0.f;
    #pragma unroll
    for (int e = 0; e < 8; e++){ p[e] = expf(part[e] - mx); sum += p[e]; }
    float inv = 1.f / sum;
    #pragma unroll
    for (int e = 0; e < 8; e++) p[e] *= inv;
    int i1 = 0;
    for (int e = 1; e < 8; e++) if (p[e] > p[i1]) i1 = e;
    int i2 = (i1 == 0) ? 1 : 0;
    for (int e = 0; e < 8; e++){ if (e != i1 && p[e] > p[i2]) i2 = e; }
    float denom = p[i1] + p[i2];
    float2 w; w.x = p[i1] / denom; w.y = p[i2] / denom;
    #pragma unroll
    for (int e = 0; e < 8; e++) p_all[t * 8 + e] = p[e];
    idx2[t] = make_int2(i1, i2);
    tokw[t] = w;
  }
}

// ---------------- finalize: counts, offsets, aux loss, tpe outputs -----------
__global__ __launch_bounds__(256) void k_finalize(const float* __restrict__ p_all,
    const int2* __restrict__ idx2, float* __restrict__ out,
    int* __restrict__ cnt, int* __restrict__ offs, int* __restrict__ cursor){
  __shared__ int sc[8];
  __shared__ float sp[8];
  const int tid = threadIdx.x;
  if (tid < 8){ sc[tid] = 0; sp[tid] = 0.f; }
  __syncthreads();
  int cl[8]; float pl[8];
  #pragma unroll
  for (int e = 0; e < 8; e++){ cl[e] = 0; pl[e] = 0.f; }
  for (int t = tid; t < T_TOK; t += 256){
    int2 id = idx2[t];
    cl[id.x]++; cl[id.y]++;
    #pragma unroll
    for (int e = 0; e < 8; e++) pl[e] += p_all[t * 8 + e];
  }
  #pragma unroll
  for (int e = 0; e < 8; e++){ atomicAdd(&sc[e], cl[e]); atomicAdd(&sp[e], pl[e]); }
  __syncthreads();
  if (tid == 0){
    float aux = 0.f; int off = 0;
    for (int e = 0; e < 8; e++){
      out[4194305 + e] = (float)sc[e];
      aux += ((float)sc[e] / 8192.0f) * (sp[e] / 4096.0f);
      offs[e] = off; cnt[e] = sc[e]; cursor[e] = 0; off += sc[e];
    }
    out[4194304] = aux * 8.0f;
  }
}

__global__ __launch_bounds__(256) void k_scatter(const int2* __restrict__ idx2,
    const float2* __restrict__ tokw, const int* __restrict__ offs,
    int* __restrict__ cursor, int* __restrict__ perm, float* __restrict__ wgt){
  int t = blockIdx.x * 256 + threadIdx.x;
  if (t >= T_TOK) return;
  int2 id = idx2[t]; float2 w = tokw[t];
  int p1 = atomicAdd(&cursor[id.x], 1);
  perm[offs[id.x] + p1] = t; wgt[offs[id.x] + p1] = w.x;
  int p2 = atomicAdd(&cursor[id.y], 1);
  perm[offs[id.y] + p2] = t; wgt[offs[id.y] + p2] = w.y;
}

// ---------------- MoE phase A: H = silu(X Wg^T) * (X Wu^T), bf16 MFMA --------
__global__ __launch_bounds__(256) void k_moe_a(
    const float* __restrict__ norm2, const float* __restrict__ Wg, const float* __restrict__ Wu,
    const int* __restrict__ cnt, const int* __restrict__ offs,
    const int* __restrict__ perm, unsigned short* __restrict__ Hbuf)
{
  int rem = blockIdx.x, e = -1, m0 = 0;
  #pragma unroll
  for (int i = 0; i < 8; i++){
    int nt = (cnt[i] + 63) >> 6;
    if (e < 0 && rem < nt){ e = i; m0 = rem << 6; }
    if (e < 0) rem -= nt;
  }
  if (e < 0) return;
  const int n0 = blockIdx.y * 128;
  const int ne = cnt[e];
  const int seg0 = offs[e];
  __shared__ unsigned short As[64][40];
  __shared__ unsigned short Bg[128][40];
  __shared__ unsigned short Bu[128][40];
  const int tid = threadIdx.x;
  const int lane = tid & 63, w = tid >> 6;
  const int wm = w >> 1, wn = w & 1;
  f32x4 accg[2][4], accu[2][4];
  #pragma unroll
  for (int i = 0; i < 2; i++)
    #pragma unroll
    for (int j = 0; j < 4; j++){
      accg[i][j] = (f32x4){0.f,0.f,0.f,0.f};
      accu[i][j] = (f32x4){0.f,0.f,0.f,0.f};
    }
  const int ar = tid >> 1, ah = (tid & 1) << 4;
  bool aval = false; const float* asrc = norm2;
  if (tid < 128){
    aval = (m0 + ar < ne);
    int token = aval ? perm[seg0 + m0 + ar] : 0;
    asrc = norm2 + (size_t)token * D_MODEL + ah;
  }
  const int br = tid & 127;
  const float* bsrc = ((tid >> 7) ? Wu : Wg) + (size_t)e * DFF * D_MODEL
                      + (size_t)(n0 + br) * D_MODEL;
  unsigned short (*Bt)[40] = (tid >> 7) ? Bu : Bg;
  const int fr = lane & 15, fk = (lane >> 4) << 3;
  for (int k0 = 0; k0 < D_MODEL; k0 += 32){
    if (tid < 128){
      u16x8 w0 = (u16x8){0,0,0,0,0,0,0,0}, w1 = w0;
      if (aval){
        float4 f0 = *(const float4*)(asrc + k0);
        float4 f1 = *(const float4*)(asrc + k0 + 4);
        float4 f2 = *(const float4*)(asrc + k0 + 8);
        float4 f3 = *(const float4*)(asrc + k0 + 12);
        w0[0]=f2bf(f0.x); w0[1]=f2bf(f0.y); w0[2]=f2bf(f0.z); w0[3]=f2bf(f0.w);
        w0[4]=f2bf(f1.x); w0[5]=f2bf(f1.y); w0[6]=f2bf(f1.z); w0[7]=f2bf(f1.w);
        w1[0]=f2bf(f2.x); w1[1]=f2bf(f2.y); w1[2]=f2bf(f2.z); w1[3]=f2bf(f2.w);
        w1[4]=f2bf(f3.x); w1[5]=f2bf(f3.y); w1[6]=f2bf(f3.z); w1[7]=f2bf(f3.w);
      }
      *(u16x8*)&As[ar][ah] = w0;
      *(u16x8*)&As[ar][ah + 8] = w1;
    }
    {
      float4 f0 = *(const float4*)(bsrc + k0);
      float4 f1 = *(const float4*)(bsrc + k0 + 4);
      float4 f2 = *(const float4*)(bsrc + k0 + 8);
      float4 f3 = *(const float4*)(bsrc + k0 + 12);
      float4 f4 = *(const float4*)(bsrc + k0 + 16);
      float4 f5 = *(const float4*)(bsrc + k0 + 20);
      float4 f6 = *(const float4*)(bsrc + k0 + 24);
      float4 f7 = *(const float4*)(bsrc + k0 + 28);
      u16x8 w0, w1, w2, w3;
      w0[0]=f2bf(f0.x); w0[1]=f2bf(f0.y); w0[2]=f2bf(f0.z); w0[3]=f2bf(f0.w);
      w0[4]=f2bf(f1.x); w0[5]=f2bf(f1.y); w0[6]=f2bf(f1.z); w0[7]=f2bf(f1.w);
      w1[0]=f2bf(f2.x); w1[1]=f2bf(f2.y); w1[2]=f2bf(f2.z); w1[3]=f2bf(f2.w);
      w1[4]=f2bf(f3.x); w1[5]=f2bf(f3.y); w1[6]=f2bf(f3.z); w1[7]=f2bf(f3.w);
      w2[0]=f2bf(f4.x); w2[1]=f2bf(f4.y); w2[2]=f2bf(f4.z); w2[3]=f2bf(f4.w);
      w2[4]=f2bf(f5.x); w2[5]=f2bf(f5.y); w2[6]=f2bf(f5.z); w2[7]=f2bf(f5.w);
      w3[0]=f2bf(f6.x); w3[1]=f2bf(f6.y); w3[2]=f2bf(f6.z); w3[3]=f2bf(f6.w);
      w3[4]=f2bf(f7.x); w3[5]=f2bf(f7.y); w3[6]=f2bf(f7.z); w3[7]=f2bf(f7.w);
      *(u16x8*)&Bt[br][0]  = w0; *(u16x8*)&Bt[br][8]  = w1;
      *(u16x8*)&Bt[br][16] = w2; *(u16x8*)&Bt[br][24] = w3;
    }
    __syncthreads();
    bf16x8 af0 = *(const bf16x8*)&As[wm*32 + fr][fk];
    bf16x8 af1 = *(const bf16x8*)&As[wm*32 + 16 + fr][fk];
    #pragma unroll
    for (int fn = 0; fn < 4; fn++){
      bf16x8 bg = *(const bf16x8*)&Bg[wn*64 + fn*16 + fr][fk];
      bf16x8 bu = *(const bf16x8*)&Bu[wn*64 + fn*16 + fr][fk];
      accg[0][fn] = __builtin_amdgcn_mfma_f32_16x16x32_bf16(af0, bg, accg[0][fn], 0, 0, 0);
      accg[1][fn] = __builtin_amdgcn_mfma_f32_16x16x32_bf16(af1, bg, accg[1][fn], 0, 0, 0);
      accu[0][fn] = __builtin_amdgcn_mfma_f32_16x16x32_bf16(af0, bu, accu[0][fn], 0, 0, 0);
      accu[1][fn] = __builtin_amdgcn_mfma_f32_16x16x32_bf16(af1, bu, accu[1][fn], 0, 0, 0);
    }
    __syncthreads();
  }
  const int r0 = (lane >> 4) << 2, cix = lane & 15;
  #pragma unroll
  for (int fm = 0; fm < 2; fm++)
    #pragma unroll
    for (int fn = 0; fn < 4; fn++)
      #pragma unroll
      for (int reg = 0; reg < 4; reg++){
        int ml2 = wm*32 + fm*16 + r0 + reg;
        if (m0 + ml2 < ne){
          int nl = wn*64 + fn*16 + cix;
          float g = accg[fm][fn][reg];
          float u = accu[fm][fn][reg];
          float h = g / (1.f + __expf(-g)) * u;
          Hbuf[(size_t)(seg0 + m0 + ml2) * DFF + n0 + nl] = f2bf(h);
        }
      }
}

// ---------------- MoE phase B: Y = H Wd^T, weighted atomic scatter-add -------
__global__ __launch_bounds__(256) void k_moe_b(
    const unsigned short* __restrict__ Hbuf, const float* __restrict__ Wd,
    const int* __restrict__ cnt, const int* __restrict__ offs,
    const int* __restrict__ perm, const float* __restrict__ wgt,
    float* __restrict__ outx)
{
  int rem = blockIdx.x, e = -1, m0 = 0;
  #pragma unroll
  for (int i = 0; i < 8; i++){
    int nt = (cnt[i] + 63) >> 6;
    if (e < 0 && rem < nt){ e = i; m0 = rem << 6; }
    if (e < 0) rem -= nt;
  }
  if (e < 0) return;
  const int n0 = blockIdx.y * 128;
  const int ne = cnt[e];
  const int seg0 = offs[e];
  __shared__ unsigned short As[64][40];
  __shared__ unsigned short Bs[128][40];
  const int tid = threadIdx.x;
  const int lane = tid & 63, w = tid >> 6;
  const int wm = w >> 1, wn = w & 1;
  f32x4 acc[2][4];
  #pragma unroll
  for (int i = 0; i < 2; i++)
    #pragma unroll
    for (int j = 0; j < 4; j++) acc[i][j] = (f32x4){0.f,0.f,0.f,0.f};
  const int ar = tid >> 1, ah = (tid & 1) << 4;
  const bool aval = (tid < 128) && (m0 + ar < ne);
  const unsigned short* asrc = aval ? (Hbuf + (size_t)(seg0 + m0 + ar) * DFF + ah) : Hbuf;
  const int br = tid >> 1, bh = (tid & 1) << 4;
  const float* bsrc = Wd + (size_t)e * D_MODEL * DFF + (size_t)(n0 + br) * DFF + bh;
  const int fr = lane & 15, fk = (lane >> 4) << 3;
  for (int k0 = 0; k0 < DFF; k0 += 32){
    if (tid < 128){
      u16x8 w0 = (u16x8){0,0,0,0,0,0,0,0}, w1 = w0;
      if (aval){
        w0 = *(const u16x8*)(asrc + k0);
        w1 = *(const u16x8*)(asrc + k0 + 8);
      }
      *(u16x8*)&As[ar][ah] = w0;
      *(u16x8*)&As[ar][ah + 8] = w1;
    }
    {
      float4 f0 = *(const float4*)(bsrc + k0);
      float4 f1 = *(const float4*)(bsrc + k0 + 4);
      float4 f2 = *(const float4*)(bsrc + k0 + 8);
      float4 f3 = *(const float4*)(bsrc + k0 + 12);
      u16x8 w0, w1;
      w0[0]=f2bf(f0.x); w0[1]=f2bf(f0.y); w0[2]=f2bf(f0.z); w0[3]=f2bf(f0.w);
      w0[4]=f2bf(f1.x); w0[5]=f2bf(f1.y); w0[6]=f2bf(f1.z); w0[7]=f2bf(f1.w);
      w1[0]=f2bf(f2.x); w1[1]=f2bf(f2.y); w1[2]=f2bf(f2.z); w1[3]=f2bf(f2.w);
      w1[4]=f2bf(f3.x); w1[5]=f2bf(f3.y); w1[6]=f2bf(f3.z); w1[7]=f2bf(f3.w);
      *(u16x8*)&Bs[br][bh] = w0;
      *(u16x8*)&Bs[br][bh + 8] = w1;
    }
    __syncthreads();
    bf16x8 af0 = *(const bf16x8*)&As[wm*32 + fr][fk];
    bf16x8 af1 = *(const bf16x8*)&As[wm*32 + 16 + fr][fk];
    #pragma unroll
    for (int fn = 0; fn < 4; fn++){
      bf16x8 bf = *(const bf16x8*)&Bs[wn*64 + fn*16 + fr][fk];
      acc[0][fn] = __builtin_amdgcn_mfma_f32_16x16x32_bf16(af0, bf, acc[0][fn], 0, 0, 0);
      acc[1][fn] = __builtin_amdgcn_mfma_f32_16x16x32_bf16(af1, bf, acc[1][fn], 0, 0, 0);
    }
    __syncthreads();
  }
  const int r0 = (lane >> 4) << 2, cix = lane & 15;
  #pragma unroll
  for (int fm = 0; fm < 2; fm++)
    #pragma unroll
    for (int reg = 0; reg < 4; reg++){
      int ml2 = wm*32 + fm*16 + r0 + reg;
      if (m0 + ml2 < ne){
        int g = seg0 + m0 + ml2;
        int token = perm[g];
        float wwt = wgt[g];
        #pragma unroll
        for (int fn = 0; fn < 4; fn++){
          int nl = wn*64 + fn*16 + cix;
          atomicAdd(&outx[(size_t)token * D_MODEL + n0 + nl], wwt * acc[fm][fn][reg]);
        }
      }
    }
}

// ---------------- launch ----------------
extern "C" void kernel_launch(void* const* d_in, const int* in_sizes, int n_in,
                              void* d_out, int out_size, void* d_ws, size_t ws_size,
                              hipStream_t stream)
{
  const float* x   = (const float*)d_in[0];
  const float* wq  = (const float*)d_in[1];
  const float* wk  = (const float*)d_in[2];
  const float* wv  = (const float*)d_in[3];
  const float* wo  = (const float*)d_in[4];
  const float* anw = (const float*)d_in[5];
  const float* fnw = (const float*)d_in[6];
  const float* rw  = (const float*)d_in[7];
  const float* Wg  = (const float*)d_in[8];
  const float* Wu  = (const float*)d_in[9];
  const float* Wd  = (const float*)d_in[10];
  float* out = (float*)d_out;

  char* ws = (char*)d_ws;
  size_t off = 0;
  auto alloc = [&](size_t bytes){ char* p = ws + off; off += (bytes + 255) & ~(size_t)255; return p; };
  // qkv FIRST: it is the only live buffer during the attention phase, so the
  // attention partial buffers can alias everything after it.
  float* qkv             = (float*)alloc((size_t)T_TOK * 1536 * 4);      // 25.2 MB
  size_t alias_base = off;
  float* norm            = (float*)alloc((size_t)T_TOK * D_MODEL * 4);   // 16.8 MB
  unsigned short* Hbuf   = (unsigned short*)alloc((size_t)8192 * DFF * 2); // 33.6 MB
  float* ctab            = (float*)alloc(2048 * 16 * 4);
  float* stab            = (float*)alloc(2048 * 16 * 4);
  float* p_all           = (float*)alloc((size_t)T_TOK * 8 * 4);
  int2* idx2             = (int2*)alloc((size_t)T_TOK * 8);
  float2* tokw           = (float2*)alloc((size_t)T_TOK * 8);
  int* cnt               = (int*)alloc(32);
  int* offs              = (int*)alloc(32);
  int* cursor            = (int*)alloc(32);
  int* perm              = (int*)alloc(8192 * 4);
  float* wgt             = (float*)alloc(8192 * 4);

  // attention KV-split partials (alias region; only qkv is live concurrently)
  int nc_max = 4;
  size_t need4 = (size_t)1024 * 4 * (4096 + 128) * 4;
  size_t avail = (ws_size > alias_base) ? (ws_size - alias_base) : 0;
  if (avail < need4) nc_max = 2;
  const int C = S_LEN / nc_max;          // 512 or 1024 kv rows per chunk
  float* Opart = (float*)(ws + alias_base);
  float* mlb   = Opart + (size_t)1024 * nc_max * 4096;

  k_rope_table<<<128, 256, 0, stream>>>(ctab, stab);
  k_rmsnorm<<<T_TOK, 256, 0, stream>>>(x, anw, norm);
  k_gemm_f32<<<dim3(12, 32), 256, 0, stream>>>(norm, D_MODEL, wq, wk, wv, 1024, 1280,
                                               qkv, 1536, nullptr, D_MODEL);
  k_rope<<<(T_TOK * 640) / 256, 256, 0, stream>>>(qkv, ctab, stab);
  k_attn_part<<<dim3(32, 16, 2 * nc_max), 64, 0, stream>>>(qkv, Opart, mlb, C);
  k_attn_comb<<<dim3(32, 16, 2), 64, 0, stream>>>(Opart, mlb, qkv, C);
  k_gemm_f32<<<dim3(8, 32), 256, 0, stream>>>(qkv, 1536, wo, nullptr, nullptr, 1 << 29, 1 << 29,
                                              out, D_MODEL, x, D_MODEL);
  k_rmsnorm<<<T_TOK, 256, 0, stream>>>(out, fnw, norm);
  k_router<<<T_TOK, 64, 0, stream>>>(norm, rw, p_all, idx2, tokw);
  k_finalize<<<1, 256, 0, stream>>>(p_all, idx2, out, cnt, offs, cursor);
  k_scatter<<<16, 256, 0, stream>>>(idx2, tokw, offs, cursor, perm, wgt);
  k_moe_a<<<dim3(136, 16), 256, 0, stream>>>(norm, Wg, Wu, cnt, offs, perm, Hbuf);
  k_moe_b<<<dim3(136, 8), 256, 0, stream>>>(Hbuf, Wd, cnt, offs, perm, wgt, out);
}